// Round 2
// baseline (270.751 us; speedup 1.0000x reference)
//
#include <hip/hip_runtime.h>

// DynamicConv2d: B=64, C=8, H=W=256, OUT_C=8, K=3, IN_FEAT=8
// out[b,oc,h,w] = sum_{ic,kh,kw} x[b,ic,h+kh-1,w+kw-1] *
//                 ( dot(dw[b,oc,:], Wg[ic*9+kh*3+kw,:]) + bg[ic*9+kh*3+kw] )

#define HC   65536   // H*W
#define WW   256

// ---------------------------------------------------------------------------
// Kernel 1: materialize per-sample conv weights into d_ws with layout
//   kern[b][ic][kh][kw][oc]  (72 contiguous floats per (b,ic))
// ---------------------------------------------------------------------------
__global__ __launch_bounds__(576) void gen_kernels(
    const float* __restrict__ dw,   // (B, 8, 8)
    const float* __restrict__ Wg,   // (72, 8)
    const float* __restrict__ bg,   // (72,)
    float* __restrict__ kern)       // (B, 576)
{
    const int b = blockIdx.x;
    const int j = threadIdx.x;
    if (j >= 576) return;
    const int ic   = j / 72;
    const int rem  = j % 72;
    const int kh   = rem / 24;
    const int rem2 = rem % 24;
    const int kw   = rem2 / 8;
    const int oc   = rem2 % 8;
    const int o    = ic * 9 + kh * 3 + kw;   // lin output index

    const float* d = dw + b * 64 + oc * 8;
    const float* g = Wg + o * 8;
    float v = bg[o];
#pragma unroll
    for (int i = 0; i < 8; ++i) v = fmaf(d[i], g[i], v);
    kern[b * 576 + j] = v;
}

// ---------------------------------------------------------------------------
// Kernel 2: conv. One wave = 2 output rows x 256 cols (64 lanes x 4 cols,
// float4 loads). Column halo via cross-lane shuffles. Block = 4 waves =
// 8 rows. Weights are wave-uniform -> compiler scalarizes into SGPRs.
// ---------------------------------------------------------------------------
__global__ __launch_bounds__(256) void dyn_conv_v2(
    const float* __restrict__ x,     // (B, 8, 256, 256)
    const float* __restrict__ kern,  // (B, 576) [ic][kh][kw][oc]
    float* __restrict__ out)         // (B, 8, 256, 256)
{
    const int b    = blockIdx.y;
    const int wave = threadIdx.x >> 6;
    const int lane = threadIdx.x & 63;
    const int row0 = blockIdx.x * 8 + wave * 2;   // this wave's 2 output rows
    const int col0 = lane << 2;                   // 4 columns per lane

    const float* xb = x + (size_t)b * 8 * HC;
    const float* Kb = kern + b * 576;
    float*       ob = out + (size_t)b * 8 * HC;

    float acc[2][8][4];
#pragma unroll
    for (int r = 0; r < 2; ++r)
#pragma unroll
        for (int oc = 0; oc < 8; ++oc)
#pragma unroll
            for (int c = 0; c < 4; ++c) acc[r][oc][c] = 0.f;

#pragma unroll 1
    for (int ic = 0; ic < 8; ++ic) {
        // 72 wave-uniform weights -> SGPRs (s_load)
        const float* Kic = Kb + ic * 72;
        float wk[72];
#pragma unroll
        for (int t = 0; t < 72; ++t) wk[t] = Kic[t];

        // load 4 input rows (row0-1 .. row0+2) as float4
        const float* xch = xb + ic * HC;
        float4 v[4];
#pragma unroll
        for (int ri = 0; ri < 4; ++ri) {
            const int ra = row0 - 1 + ri;       // wave-uniform condition
            if (ra >= 0 && ra < 256)
                v[ri] = *(const float4*)(xch + ra * WW + col0);
            else
                v[ri] = make_float4(0.f, 0.f, 0.f, 0.f);
        }

#pragma unroll
        for (int ri = 0; ri < 4; ++ri) {
            // column halo from neighbor lanes
            float xl = __shfl_up(v[ri].w, 1);
            if (lane == 0) xl = 0.f;            // image left edge
            float xr = __shfl_down(v[ri].x, 1);
            if (lane == 63) xr = 0.f;           // image right edge
            const float xv[6] = {xl, v[ri].x, v[ri].y, v[ri].z, v[ri].w, xr};

            // input row (row0-1+ri) feeds output row r = ri - kh
#pragma unroll
            for (int kh = 0; kh < 3; ++kh) {
                const int r = ri - kh;
                if (r < 0 || r > 1) continue;   // compile-time pruned
#pragma unroll
                for (int kw = 0; kw < 3; ++kw) {
                    const float* wo = &wk[kh * 24 + kw * 8];
#pragma unroll
                    for (int oc = 0; oc < 8; ++oc) {
                        const float w8 = wo[oc];   // SGPR operand
#pragma unroll
                        for (int c = 0; c < 4; ++c)
                            acc[r][oc][c] = fmaf(xv[c + kw], w8, acc[r][oc][c]);
                    }
                }
            }
        }
    }

#pragma unroll
    for (int r = 0; r < 2; ++r) {
        float* orow = ob + (row0 + r) * WW + col0;
#pragma unroll
        for (int oc = 0; oc < 8; ++oc) {
            float4 o4 = make_float4(acc[r][oc][0], acc[r][oc][1],
                                    acc[r][oc][2], acc[r][oc][3]);
            *(float4*)(orow + oc * HC) = o4;
        }
    }
}

// ---------------------------------------------------------------------------
// Fallback (ws too small): old fused variant, weights in LDS.
// ---------------------------------------------------------------------------
#define RPB 8
__global__ __launch_bounds__(256) void dyn_conv_fused(
    const float* __restrict__ x,
    const float* __restrict__ dw,
    const float* __restrict__ Wg,
    const float* __restrict__ bg,
    float* __restrict__ out)
{
    __shared__ float kl[576];
    const int b  = blockIdx.y;
    const int h0 = blockIdx.x * RPB;
    const int w  = threadIdx.x;

    for (int j = threadIdx.x; j < 576; j += 256) {
        const int ic   = j / 72;
        const int rem  = j % 72;
        const int kh   = rem / 24;
        const int rem2 = rem % 24;
        const int kw   = rem2 / 8;
        const int oc   = rem2 % 8;
        const int o    = ic * 9 + kh * 3 + kw;
        const float* d = dw + b * 64 + oc * 8;
        const float* g = Wg + o * 8;
        float v = bg[o];
#pragma unroll
        for (int i = 0; i < 8; ++i) v = fmaf(d[i], g[i], v);
        kl[j] = v;
    }
    __syncthreads();

    const float* xb = x + (size_t)b * 8 * HC;
    float*       ob = out + (size_t)b * 8 * HC;

    float acc[RPB][8];
#pragma unroll
    for (int r = 0; r < RPB; ++r)
#pragma unroll
        for (int oc = 0; oc < 8; ++oc) acc[r][oc] = 0.f;

#pragma unroll 1
    for (int ic = 0; ic < 8; ++ic) {
        float wk[72];
        const float* Kic = &kl[ic * 72];
#pragma unroll
        for (int t = 0; t < 72; ++t) wk[t] = Kic[t];

        const float* xch = xb + ic * HC;
#pragma unroll
        for (int ri = 0; ri < RPB + 2; ++ri) {
            const int row = h0 - 1 + ri;
            float xm = 0.f, xc = 0.f, xp = 0.f;
            if (row >= 0 && row < 256) {
                const float* xr = xch + row * WW;
                xc = xr[w];
                xm = (w > 0)   ? xr[w - 1] : 0.f;
                xp = (w < 255) ? xr[w + 1] : 0.f;
            }
#pragma unroll
            for (int kh = 0; kh < 3; ++kh) {
                const int ro = ri - kh;
                if (ro < 0 || ro >= RPB) continue;
                const float* wr = &wk[kh * 24];
#pragma unroll
                for (int oc = 0; oc < 8; ++oc) {
                    float a = acc[ro][oc];
                    a = fmaf(xm, wr[0 * 8 + oc], a);
                    a = fmaf(xc, wr[1 * 8 + oc], a);
                    a = fmaf(xp, wr[2 * 8 + oc], a);
                    acc[ro][oc] = a;
                }
            }
        }
    }

    const int hw0 = h0 * WW + w;
#pragma unroll
    for (int oc = 0; oc < 8; ++oc) {
        float* orow = ob + oc * HC + hw0;
#pragma unroll
        for (int r = 0; r < RPB; ++r) orow[r * WW] = acc[r][oc];
    }
}

extern "C" void kernel_launch(void* const* d_in, const int* in_sizes, int n_in,
                              void* d_out, int out_size, void* d_ws, size_t ws_size,
                              hipStream_t stream) {
    const float* x  = (const float*)d_in[0];  // (64,8,256,256)
    const float* dw = (const float*)d_in[1];  // (64,8,8)
    const float* Wg = (const float*)d_in[2];  // (72,8)
    const float* bg = (const float*)d_in[3];  // (72,)
    float* out = (float*)d_out;

    if (ws_size >= (size_t)(64 * 576 * sizeof(float))) {
        float* kern = (float*)d_ws;
        gen_kernels<<<dim3(64), dim3(576), 0, stream>>>(dw, Wg, bg, kern);
        dyn_conv_v2<<<dim3(32, 64), dim3(256), 0, stream>>>(x, kern, out);
    } else {
        dyn_conv_fused<<<dim3(256 / RPB, 64), dim3(256), 0, stream>>>(x, dw, Wg, bg, out);
    }
}

// Round 3
// 264.407 us; speedup vs baseline: 1.0240x; 1.0240x over previous
//
#include <hip/hip_runtime.h>

// DynamicConv2d: B=64, C=8, H=W=256, OUT_C=8, K=3, IN_FEAT=8
// out[b,oc,h,w] = sum_{ic,kh,kw} x[b,ic,h+kh-1,w+kw-1] *
//                 ( dot(dw[b,oc,:], Wg[ic*9+kh*3+kw,:]) + bg[ic*9+kh*3+kw] )

#define HC   65536   // H*W
#define WW   256

// ---------------------------------------------------------------------------
// Kernel 1: materialize per-sample conv weights into d_ws with layout
//   kern[b][ic][kh][kw][oc]  (72 contiguous floats per (b,ic))
// ---------------------------------------------------------------------------
__global__ __launch_bounds__(576) void gen_kernels(
    const float* __restrict__ dw,   // (B, 8, 8)
    const float* __restrict__ Wg,   // (72, 8)
    const float* __restrict__ bg,   // (72,)
    float* __restrict__ kern)       // (B, 576)
{
    const int b = blockIdx.x;
    const int j = threadIdx.x;
    if (j >= 576) return;
    const int ic   = j / 72;
    const int rem  = j % 72;
    const int kh   = rem / 24;
    const int rem2 = rem % 24;
    const int kw   = rem2 / 8;
    const int oc   = rem2 % 8;
    const int o    = ic * 9 + kh * 3 + kw;   // lin output index

    const float* d = dw + b * 64 + oc * 8;
    const float* g = Wg + o * 8;
    float v = bg[o];
#pragma unroll
    for (int i = 0; i < 8; ++i) v = fmaf(d[i], g[i], v);
    kern[b * 576 + j] = v;
}

// ---------------------------------------------------------------------------
// Kernel 2: conv, software-pipelined over ic. One wave = 2 output rows x
// 256 cols (64 lanes x 4 cols, float4 loads). Column halo via shuffles.
// Rows for ic+1 prefetched into a second register buffer during ic's FMAs.
// ---------------------------------------------------------------------------
__global__ __launch_bounds__(256) void dyn_conv_v3(
    const float* __restrict__ x,     // (B, 8, 256, 256)
    const float* __restrict__ kern,  // (B, 576) [ic][kh][kw][oc]
    float* __restrict__ out)         // (B, 8, 256, 256)
{
    const int b    = blockIdx.y;
    const int wave = threadIdx.x >> 6;
    const int lane = threadIdx.x & 63;
    const int row0 = blockIdx.x * 8 + wave * 2;   // this wave's 2 output rows
    const int col0 = lane << 2;                   // 4 columns per lane

    const float* xb = x + (size_t)b * 8 * HC;
    const float* Kb = kern + b * 576;
    float*       ob = out + (size_t)b * 8 * HC;

    const bool le = (lane == 0);
    const bool re = (lane == 63);

    float acc[2][8][4];
#pragma unroll
    for (int r = 0; r < 2; ++r)
#pragma unroll
        for (int oc = 0; oc < 8; ++oc)
#pragma unroll
            for (int c = 0; c < 4; ++c) acc[r][oc][c] = 0.f;

    // ---- prefetch ic=0 rows ----
    float4 nxt[4];
#pragma unroll
    for (int ri = 0; ri < 4; ++ri) {
        const int ra = row0 - 1 + ri;            // wave-uniform condition
        nxt[ri] = (ra >= 0 && ra < 256)
                      ? *(const float4*)(xb + ra * WW + col0)
                      : make_float4(0.f, 0.f, 0.f, 0.f);
    }

#pragma unroll 1
    for (int ic = 0; ic < 8; ++ic) {
        // consume prefetched rows
        float4 cur[4];
#pragma unroll
        for (int ri = 0; ri < 4; ++ri) cur[ri] = nxt[ri];

        // issue prefetch for ic+1 (overlaps with this iter's FMA burst)
        if (ic < 7) {
            const float* xch = xb + (ic + 1) * HC;
#pragma unroll
            for (int ri = 0; ri < 4; ++ri) {
                const int ra = row0 - 1 + ri;
                nxt[ri] = (ra >= 0 && ra < 256)
                              ? *(const float4*)(xch + ra * WW + col0)
                              : make_float4(0.f, 0.f, 0.f, 0.f);
            }
        }

        // 72 wave-uniform weights -> SGPRs
        const float* Kic = Kb + ic * 72;
        float wk[72];
#pragma unroll
        for (int t = 0; t < 72; ++t) wk[t] = Kic[t];

        // all column-halo shuffles up front (lgkm latency overlaps first FMAs)
        float xl[4], xr[4];
#pragma unroll
        for (int ri = 0; ri < 4; ++ri) {
            float l = __shfl_up(cur[ri].w, 1);
            float r = __shfl_down(cur[ri].x, 1);
            xl[ri] = le ? 0.f : l;
            xr[ri] = re ? 0.f : r;
        }

#pragma unroll
        for (int ri = 0; ri < 4; ++ri) {
            const float xv[6] = {xl[ri], cur[ri].x, cur[ri].y,
                                 cur[ri].z, cur[ri].w, xr[ri]};
            // input row (row0-1+ri) feeds output row r = ri - kh
#pragma unroll
            for (int kh = 0; kh < 3; ++kh) {
                const int r = ri - kh;
                if (r < 0 || r > 1) continue;   // compile-time pruned
#pragma unroll
                for (int kw = 0; kw < 3; ++kw) {
                    const float* wo = &wk[kh * 24 + kw * 8];
#pragma unroll
                    for (int oc = 0; oc < 8; ++oc) {
                        const float w8 = wo[oc];   // SGPR operand
#pragma unroll
                        for (int c = 0; c < 4; ++c)
                            acc[r][oc][c] = fmaf(xv[c + kw], w8, acc[r][oc][c]);
                    }
                }
            }
        }
    }

#pragma unroll
    for (int r = 0; r < 2; ++r) {
        float* orow = ob + (row0 + r) * WW + col0;
#pragma unroll
        for (int oc = 0; oc < 8; ++oc) {
            float4 o4 = make_float4(acc[r][oc][0], acc[r][oc][1],
                                    acc[r][oc][2], acc[r][oc][3]);
            *(float4*)(orow + oc * HC) = o4;
        }
    }
}

// ---------------------------------------------------------------------------
// Fallback (ws too small): fused variant, weights in LDS.
// ---------------------------------------------------------------------------
#define RPB 8
__global__ __launch_bounds__(256) void dyn_conv_fused(
    const float* __restrict__ x,
    const float* __restrict__ dw,
    const float* __restrict__ Wg,
    const float* __restrict__ bg,
    float* __restrict__ out)
{
    __shared__ float kl[576];
    const int b  = blockIdx.y;
    const int h0 = blockIdx.x * RPB;
    const int w  = threadIdx.x;

    for (int j = threadIdx.x; j < 576; j += 256) {
        const int ic   = j / 72;
        const int rem  = j % 72;
        const int kh   = rem / 24;
        const int rem2 = rem % 24;
        const int kw   = rem2 / 8;
        const int oc   = rem2 % 8;
        const int o    = ic * 9 + kh * 3 + kw;
        const float* d = dw + b * 64 + oc * 8;
        const float* g = Wg + o * 8;
        float v = bg[o];
#pragma unroll
        for (int i = 0; i < 8; ++i) v = fmaf(d[i], g[i], v);
        kl[j] = v;
    }
    __syncthreads();

    const float* xb = x + (size_t)b * 8 * HC;
    float*       ob = out + (size_t)b * 8 * HC;

    float acc[RPB][8];
#pragma unroll
    for (int r = 0; r < RPB; ++r)
#pragma unroll
        for (int oc = 0; oc < 8; ++oc) acc[r][oc] = 0.f;

#pragma unroll 1
    for (int ic = 0; ic < 8; ++ic) {
        float wk[72];
        const float* Kic = &kl[ic * 72];
#pragma unroll
        for (int t = 0; t < 72; ++t) wk[t] = Kic[t];

        const float* xch = xb + ic * HC;
#pragma unroll
        for (int ri = 0; ri < RPB + 2; ++ri) {
            const int row = h0 - 1 + ri;
            float xm = 0.f, xc = 0.f, xp = 0.f;
            if (row >= 0 && row < 256) {
                const float* xr = xch + row * WW;
                xc = xr[w];
                xm = (w > 0)   ? xr[w - 1] : 0.f;
                xp = (w < 255) ? xr[w + 1] : 0.f;
            }
#pragma unroll
            for (int kh = 0; kh < 3; ++kh) {
                const int ro = ri - kh;
                if (ro < 0 || ro >= RPB) continue;
                const float* wr = &wk[kh * 24];
#pragma unroll
                for (int oc = 0; oc < 8; ++oc) {
                    float a = acc[ro][oc];
                    a = fmaf(xm, wr[0 * 8 + oc], a);
                    a = fmaf(xc, wr[1 * 8 + oc], a);
                    a = fmaf(xp, wr[2 * 8 + oc], a);
                    acc[ro][oc] = a;
                }
            }
        }
    }

    const int hw0 = h0 * WW + w;
#pragma unroll
    for (int oc = 0; oc < 8; ++oc) {
        float* orow = ob + oc * HC + hw0;
#pragma unroll
        for (int r = 0; r < RPB; ++r) orow[r * WW] = acc[r][oc];
    }
}

extern "C" void kernel_launch(void* const* d_in, const int* in_sizes, int n_in,
                              void* d_out, int out_size, void* d_ws, size_t ws_size,
                              hipStream_t stream) {
    const float* x  = (const float*)d_in[0];  // (64,8,256,256)
    const float* dw = (const float*)d_in[1];  // (64,8,8)
    const float* Wg = (const float*)d_in[2];  // (72,8)
    const float* bg = (const float*)d_in[3];  // (72,)
    float* out = (float*)d_out;

    if (ws_size >= (size_t)(64 * 576 * sizeof(float))) {
        float* kern = (float*)d_ws;
        gen_kernels<<<dim3(64), dim3(576), 0, stream>>>(dw, Wg, bg, kern);
        dyn_conv_v3<<<dim3(32, 64), dim3(256), 0, stream>>>(x, kern, out);
    } else {
        dyn_conv_fused<<<dim3(256 / RPB, 64), dim3(256), 0, stream>>>(x, dw, Wg, bg, out);
    }
}